// Round 1
// baseline (42.606 us; speedup 1.0000x reference)
//
#include <hip/hip_runtime.h>
#include <hip/hip_bf16.h>

// out[i] = a[i, argmax_j(z[i, 3+j])], j in {0,1,2}, first-max tie-break.
// B = 4194304 rows, z row = 8 f32, a row = 3 f32.
// Each thread handles 4 rows => all loads/stores are aligned float4:
//   z: 4 rows * 32B = 128B = 8 x float4
//   a: 4 rows * 12B =  48B = 3 x float4
//   out: 4 f32 = 1 x float4

__global__ __launch_bounds__(256) void color_val_kernel(
    const float* __restrict__ z,
    const float* __restrict__ a,
    float* __restrict__ out,
    int nquads)  // = B/4
{
    int t = blockIdx.x * blockDim.x + threadIdx.x;
    if (t >= nquads) return;

    const float4* z4 = reinterpret_cast<const float4*>(z) + (size_t)t * 8;
    const float4* a4 = reinterpret_cast<const float4*>(a) + (size_t)t * 3;

    float4 zl[8];
#pragma unroll
    for (int k = 0; k < 8; ++k) zl[k] = z4[k];

    float4 av0 = a4[0];
    float4 av1 = a4[1];
    float4 av2 = a4[2];
    // a values for the 4 rows, flattened (compile-time indexed only)
    float aa[12] = {av0.x, av0.y, av0.z, av0.w,
                    av1.x, av1.y, av1.z, av1.w,
                    av2.x, av2.y, av2.z, av2.w};

    float4 o;
    float* op = &o.x;
#pragma unroll
    for (int r = 0; r < 4; ++r) {
        // row r of this quad: z elements 3,4,5 live at
        //   zl[2r].w (elem 3), zl[2r+1].x (elem 4), zl[2r+1].y (elem 5)
        float c0 = zl[2 * r].w;
        float c1 = zl[2 * r + 1].x;
        float c2 = zl[2 * r + 1].y;
        float m   = c0;
        float val = aa[r * 3 + 0];
        if (c1 > m) { m = c1; val = aa[r * 3 + 1]; }  // strict > => first-max
        if (c2 > m) {          val = aa[r * 3 + 2]; }
        op[r] = val;
    }

    reinterpret_cast<float4*>(out)[t] = o;
}

extern "C" void kernel_launch(void* const* d_in, const int* in_sizes, int n_in,
                              void* d_out, int out_size, void* d_ws, size_t ws_size,
                              hipStream_t stream) {
    const float* z = (const float*)d_in[0];  // (B, 8) f32
    const float* a = (const float*)d_in[1];  // (B, 3) f32
    float* out = (float*)d_out;              // (B,)  f32

    int B = out_size;          // 4194304
    int nquads = B / 4;        // 1048576 (B divisible by 4)
    int block = 256;
    int grid = (nquads + block - 1) / block;
    color_val_kernel<<<grid, block, 0, stream>>>(z, a, out, nquads);
}

// Round 2
// 34.287 us; speedup vs baseline: 1.2426x; 1.2426x over previous
//
#include <hip/hip_runtime.h>
#include <hip/hip_bf16.h>

// out[i] = a[i, argmax_j(z[i, 3+j])], j in {0,1,2}, first-max tie-break.
// B = 4194304 rows; z row = 8 f32 (32B), a row = 3 f32 (12B).
//
// All global accesses are LANE-contiguous (1024B / 512B per wave instr):
// stage tiles through LDS, then each thread computes rows t and t+256.
// z LDS row stride = 9 words -> read banks (9t+c)%32, gcd(9,32)=1 -> 2-way (free).

#define ROWS_PER_BLOCK 512
#define NTHREADS 256

__global__ __launch_bounds__(NTHREADS) void color_val_lds(
    const float* __restrict__ z,
    const float* __restrict__ a,
    float* __restrict__ out)
{
    __shared__ __align__(16) float zs[ROWS_PER_BLOCK * 9];  // 18 KB
    __shared__ __align__(16) float as_[ROWS_PER_BLOCK * 3]; //  6 KB

    const int t = threadIdx.x;
    const size_t rowBase = (size_t)blockIdx.x * ROWS_PER_BLOCK;

    // ---- stage z: 1024 float4 per block, contiguous per instruction ----
    const float4* zg = reinterpret_cast<const float4*>(z) + rowBase * 2;
#pragma unroll
    for (int q = 0; q < 4; ++q) {
        int f = q * NTHREADS + t;       // float4 index within tile
        float4 v = zg[f];
        int r = f >> 1;                 // row within tile
        int h = (f & 1) * 4;            // which half of the row
        float* p = &zs[r * 9 + h];
        p[0] = v.x; p[1] = v.y; p[2] = v.z; p[3] = v.w;
    }

    // ---- stage a: 768 float2 per block, contiguous per instruction ----
    const float2* ag = reinterpret_cast<const float2*>(a) + (rowBase * 3) / 2;
    float2* as2 = reinterpret_cast<float2*>(as_);
#pragma unroll
    for (int q = 0; q < 3; ++q) {
        int p2 = q * NTHREADS + t;
        as2[p2] = ag[p2];
    }

    __syncthreads();

    // ---- compute: thread t handles rows t and t+256 (lanes 1 row apart) ----
#pragma unroll
    for (int k = 0; k < 2; ++k) {
        int r = k * NTHREADS + t;
        const float* zr = &zs[r * 9];
        float c0 = zr[3];
        float c1 = zr[4];
        float c2 = zr[5];
        const float* ar = &as_[r * 3];
        float val = ar[0];
        float m = c0;
        if (c1 > m) { m = c1; val = ar[1]; }   // strict > => first-max tie-break
        if (c2 > m) {          val = ar[2]; }
        out[rowBase + r] = val;                 // dword store, lane-contiguous
    }
}

// generic tail (unused for B=4194304, kept for safety)
__global__ void color_val_tail(
    const float* __restrict__ z,
    const float* __restrict__ a,
    float* __restrict__ out,
    size_t start, size_t B)
{
    size_t i = start + blockIdx.x * blockDim.x + threadIdx.x;
    if (i >= B) return;
    float c0 = z[i * 8 + 3], c1 = z[i * 8 + 4], c2 = z[i * 8 + 5];
    float val = a[i * 3 + 0];
    float m = c0;
    if (c1 > m) { m = c1; val = a[i * 3 + 1]; }
    if (c2 > m) {          val = a[i * 3 + 2]; }
    out[i] = val;
}

extern "C" void kernel_launch(void* const* d_in, const int* in_sizes, int n_in,
                              void* d_out, int out_size, void* d_ws, size_t ws_size,
                              hipStream_t stream) {
    const float* z = (const float*)d_in[0];  // (B, 8) f32
    const float* a = (const float*)d_in[1];  // (B, 3) f32
    float* out = (float*)d_out;              // (B,)  f32

    size_t B = (size_t)out_size;             // 4194304
    size_t nfull = B / ROWS_PER_BLOCK;       // 8192
    size_t rem = B % ROWS_PER_BLOCK;         // 0

    if (nfull > 0)
        color_val_lds<<<(int)nfull, NTHREADS, 0, stream>>>(z, a, out);
    if (rem > 0) {
        size_t start = nfull * ROWS_PER_BLOCK;
        int blocks = (int)((rem + 255) / 256);
        color_val_tail<<<blocks, 256, 0, stream>>>(z, a, out, start, B);
    }
}